// Round 7
// baseline (300.628 us; speedup 1.0000x reference)
//
#include <hip/hip_runtime.h>
#include <math.h>

#define NN 8192
#define CF 192
#define KNN 9
#define NSPL 4

__device__ __forceinline__ int group_start(int g) {
    // smallest i with batch[i]==g :  ceil(8191*g/8), capped at 8192
    int s = (8191 * g + 7) >> 3;
    return s > 8192 ? 8192 : s;
}

__device__ __forceinline__ float disf(int d) {
    return d > 0 ? 1.0f / sqrtf((float)d) : 0.0f;
}

// ---------------------------------------------------------------- transpose + sq
// x [8,192,32,32] -> xf [8192][192]; also accumulates sq[node] = ||x_f||^2
// via per-32-channel partial sums (half-wave shuffle reduce + atomicAdd).
// sq must be zeroed before launch (memsetAsync covers sq+deg).
__global__ __launch_bounds__(256) void transpose_kernel(
    const float* __restrict__ x, float* __restrict__ xf, float* __restrict__ sq)
{
    __shared__ float tile[32][65];
    int b = blockIdx.x, ct = blockIdx.y, ht = blockIdx.z;
    int c0 = ct * 32, hw0 = ht * 64;
    int tid = threadIdx.x;
#pragma unroll
    for (int p = 0; p < 8; ++p) {
        int c  = p * 4 + (tid >> 6);
        int hw = tid & 63;
        tile[c][hw] = x[(size_t)b * 196608 + (size_t)(c0 + c) * 1024 + hw0 + hw];
    }
    __syncthreads();
#pragma unroll
    for (int p = 0; p < 8; ++p) {
        int hw = p * 8 + (tid >> 5);
        int cc = tid & 31;
        float v = tile[cc][hw];
        xf[(size_t)(b * 1024 + hw0 + hw) * CF + c0 + cc] = v;
        float s = v * v;                 // partial ||.||^2 over this 32-ch slice
#pragma unroll
        for (int off = 16; off > 0; off >>= 1) s += __shfl_xor(s, off, 64);
        if (cc == 0) atomicAdd(&sq[b * 1024 + hw0 + hw], s);
    }
}

// ---------------------------------------------------------------- kNN partial
// grid: 9 groups x 16 query-blocks(64 q) x 4 candidate-splits(256 c) = 576
// blocks; 512 heavy blocks = exactly 2/CU (LDS 55 KB). 8x8 micro-tile:
// 64 B LDS per 64 FMAs -> LDS pipe demand = 128 B/cyc = peak (was 1.5x over
// with the 4x8 tile). (256,2) -> 256-VGPR budget, acc[8][8] can't spill.
__global__ __launch_bounds__(256, 2) void knn_kernel(
    const float* __restrict__ xf, const float* __restrict__ sq,
    float* __restrict__ pk_d, int* __restrict__ pk_i)
{
    int bid = blockIdx.x;
    int g = bid >> 6;
    int rem = bid & 63;
    int qb = rem >> 2;
    int split = rem & 3;
    int gs = group_start(g);
    int gsize = group_start(g + 1) - gs;
    int q0 = qb * 64;
    int nq = gsize - q0; if (nq > 64) nq = 64;
    if (nq <= 0) return;                 // block-uniform; q's covered elsewhere
    int c0 = split * 256;
    int ncc = gsize - c0; if (ncc > 256) ncc = 256;

    int tid = threadIdx.x;

    float td[KNN]; int ti[KNN];
#pragma unroll
    for (int j = 0; j < KNN; ++j) { td[j] = __builtin_inff(); ti[j] = -1; }

    if (ncc <= 0) {                      // block-uniform: empty split
        if (tid < nq) {
            int q = gs + q0 + tid;
            size_t base = ((size_t)q * NSPL + split) * KNN;
#pragma unroll
            for (int j = 0; j < KNN; ++j) { pk_d[base + j] = td[j]; pk_i[base + j] = ti[j]; }
        }
        return;
    }

    // staging region (20992 B), overlaid by phase-1 partial lists (9360+9360 B)
    __shared__ __align__(16) char smem[20992];
    float (*As)[68]  = (float(*)[68])smem;                    // 16x68x4  = 4352
    float (*Bs)[260] = (float(*)[260])(smem + 4352);          // 16x260x4 = 16640
    float (*ld)[KNN][65] = (float(*)[KNN][65])smem;           // 4x9x65x4 = 9360
    int   (*li)[KNN][65] = (int(*)[KNN][65])(smem + 9360);    // 9360
    __shared__ float Ds[64][133];        // dot tile, one 128-col half at a time
    __shared__ float sqc_s[256];
    __shared__ float sqq_s[64];

    int ty = tid >> 5;                   // row group: rows ty*8 .. +7
    int tx = tid & 31;                   // cols tx*4 (half0), 128+tx*4 (half1)

    if (tid < 64) {
        int qo = q0 + tid; if (qo > gsize - 1) qo = gsize - 1;
        sqq_s[tid] = sq[gs + qo];
    }
    {
        int co = c0 + tid;
        sqc_s[tid] = (tid < ncc) ? sq[gs + co] : __builtin_inff();
    }

    float acc[8][8];
#pragma unroll
    for (int i = 0; i < 8; ++i)
#pragma unroll
        for (int j = 0; j < 8; ++j) acc[i][j] = 0.0f;

    for (int kb = 0; kb < 12; ++kb) {
        __syncthreads();
        {                                // As: 64 q-rows x 4 float4 = 256 thr
            int r = tid >> 2, c4 = (tid & 3) * 4;
            int qo = q0 + r; if (qo > gsize - 1) qo = gsize - 1;
            float4 v = *(const float4*)(xf + (size_t)(gs + qo) * CF + kb * 16 + c4);
            As[c4 + 0][r] = v.x; As[c4 + 1][r] = v.y;
            As[c4 + 2][r] = v.z; As[c4 + 3][r] = v.w;
        }
#pragma unroll
        for (int p2 = 0; p2 < 4; ++p2) { // Bs: 256 c-rows x 4 float4
            int t = tid + 256 * p2;
            int r = t >> 2, c4 = (t & 3) * 4;
            int co = c0 + r; if (co > gsize - 1) co = gsize - 1;
            float4 v = *(const float4*)(xf + (size_t)(gs + co) * CF + kb * 16 + c4);
            Bs[c4 + 0][r] = v.x; Bs[c4 + 1][r] = v.y;
            Bs[c4 + 2][r] = v.z; Bs[c4 + 3][r] = v.w;
        }
        __syncthreads();
#pragma unroll
        for (int k = 0; k < 16; ++k) {
            float4 a0 = *(const float4*)&As[k][ty * 8];
            float4 a1 = *(const float4*)&As[k][ty * 8 + 4];
            float4 b0 = *(const float4*)&Bs[k][tx * 4];
            float4 b1 = *(const float4*)&Bs[k][128 + tx * 4];
            float aa[8] = {a0.x, a0.y, a0.z, a0.w, a1.x, a1.y, a1.z, a1.w};
            float bb[8] = {b0.x, b0.y, b0.z, b0.w, b1.x, b1.y, b1.z, b1.w};
#pragma unroll
            for (int i = 0; i < 8; ++i)
#pragma unroll
                for (int j = 0; j < 8; ++j)
                    acc[i][j] = fmaf(aa[i], bb[j], acc[i][j]);
        }
    }

    // ---- selection over two 128-column halves (candidates in index order)
    for (int h = 0; h < 2; ++h) {
        int hb = h * 128;
        __syncthreads();                 // FMA reads / prev phase2 done
        // write this half's dot products: all 256 threads, stride-133 rows
#pragma unroll
        for (int i = 0; i < 8; ++i)
            *(float4*)&Ds[ty * 8 + i][tx * 4] =
                make_float4(acc[i][h * 4 + 0], acc[i][h * 4 + 1],
                            acc[i][h * 4 + 2], acc[i][h * 4 + 3]);
        __syncthreads();
        // phase1: thread -> (query q = tid&63, chunk ch = tid>>6 of 32 cands)
        {
            int q = tid & 63, ch = tid >> 6;
            float sqq = sqq_s[q];
            float pd[KNN]; int pi[KNN];
#pragma unroll
            for (int j = 0; j < KNN; ++j) { pd[j] = __builtin_inff(); pi[j] = -1; }
            for (int j32 = 0; j32 < 32; ++j32) {
                int c = ch * 32 + j32;
                float d = (sqq - 2.0f * Ds[q][c]) + sqc_s[hb + c];  // inf pad
                if (d < pd[KNN - 1]) {
                    pd[KNN - 1] = d; pi[KNN - 1] = gs + c0 + hb + c;
#pragma unroll
                    for (int j = KNN - 1; j > 0; --j) {
                        if (pd[j] < pd[j - 1]) {
                            float tf = pd[j]; pd[j] = pd[j - 1]; pd[j - 1] = tf;
                            int tn = pi[j]; pi[j] = pi[j - 1]; pi[j - 1] = tn;
                        }
                    }
                }
            }
#pragma unroll
            for (int j = 0; j < KNN; ++j) { ld[ch][j][q] = pd[j]; li[ch][j][q] = pi[j]; }
        }
        __syncthreads();
        // phase2: 64 threads merge 4 sorted lists (index order; early break)
        if (tid < 64) {
            for (int ch = 0; ch < 4; ++ch) {
#pragma unroll
                for (int j0 = 0; j0 < KNN; ++j0) {
                    float d = ld[ch][j0][tid];
                    if (!(d < td[KNN - 1])) break;   // sorted: rest can't insert
                    int id = li[ch][j0][tid];
                    td[KNN - 1] = d; ti[KNN - 1] = id;
#pragma unroll
                    for (int j = KNN - 1; j > 0; --j) {
                        if (td[j] < td[j - 1]) {
                            float tf = td[j]; td[j] = td[j - 1]; td[j - 1] = tf;
                            int tn = ti[j]; ti[j] = ti[j - 1]; ti[j - 1] = tn;
                        }
                    }
                }
            }
        }
    }

    if (tid < nq) {
        int q = gs + q0 + tid;
        size_t base = ((size_t)q * NSPL + split) * KNN;
#pragma unroll
        for (int j = 0; j < KNN; ++j) { pk_d[base + j] = td[j]; pk_i[base + j] = ti[j]; }
    }
}

// ---------------------------------------------------------------- merge + deg
__global__ __launch_bounds__(256) void merge_kernel(
    const float* __restrict__ pk_d, const int* __restrict__ pk_i,
    int* __restrict__ edges, int* __restrict__ deg)
{
    int q = blockIdx.x * 256 + threadIdx.x;
    if (q >= NN) return;
    float td[KNN]; int ti[KNN];
#pragma unroll
    for (int j = 0; j < KNN; ++j) { td[j] = __builtin_inff(); ti[j] = -1; }
    for (int s = 0; s < NSPL; ++s) {       // split order = index order (stable)
        size_t base = ((size_t)q * NSPL + s) * KNN;
#pragma unroll
        for (int j0 = 0; j0 < KNN; ++j0) {
            float d = pk_d[base + j0]; int id = pk_i[base + j0];
            if (d < td[KNN - 1]) {
                td[KNN - 1] = d; ti[KNN - 1] = id;
#pragma unroll
                for (int j = KNN - 1; j > 0; --j) {
                    if (td[j] < td[j - 1]) {
                        float tf = td[j]; td[j] = td[j - 1]; td[j - 1] = tf;
                        int tn = ti[j]; ti[j] = ti[j - 1]; ti[j - 1] = tn;
                    }
                }
            }
        }
    }
#pragma unroll
    for (int j = 0; j < KNN; ++j) {
        int id = ti[j];                   // -1 <=> invalid (d == inf)
        edges[q * KNN + j] = id;
        if (id >= 0 && id != q) atomicAdd(&deg[id], 1);
    }
}

// ---------------------------------------------------------------- fused Tx1 + out GEMM
// One block per 16-row stripe (512 blocks). W0/W1 k-tiles staged together so
// both matmuls accumulate in one kb sweep; W prefetched into registers (OK
// here: (256,2) -> 256-VGPR budget, no spill). LDS 50.3 KB.
__global__ __launch_bounds__(256, 2) void out_kernel(
    const float* __restrict__ xf, const int* __restrict__ edges,
    const int* __restrict__ deg, const float* __restrict__ W0,
    const float* __restrict__ W1, const float* __restrict__ bias,
    float* __restrict__ out)
{
    __shared__ float Ax[2][16][CF];      // [0]=xf rows, [1]=Tx1 rows (24.6 KB)
    __shared__ float Ws[2][16][CF];      // W0/W1 k-tiles (24.6 KB)
    __shared__ float coef_s[16][KNN];
    __shared__ int   nb_s[16][KNN];

    int r0 = blockIdx.x * 16;
    int tid = threadIdx.x;

    // W prefetch setup: 1536 float4 per kb tile, 6 per thread
    const float* wsrc[6];
    int ww[6], wr[6], wc[6];
    float4 pw[6];
#pragma unroll
    for (int p = 0; p < 6; ++p) {
        int f = p * 256 + tid;
        ww[p] = f / 768; wr[p] = (f % 768) / 48; wc[p] = (f % 48) * 4;
        wsrc[p] = (ww[p] ? W1 : W0) + (size_t)wr[p] * CF + wc[p];
        pw[p] = *(const float4*)(wsrc[p]);          // kb = 0
    }

    // stage xf rows: 16 rows x 48 float4 = 768
    for (int t = tid; t < 768; t += 256) {
        int i = t / 48, c4 = (t % 48) * 4;
        *(float4*)&Ax[0][i][c4] = *(const float4*)&xf[(size_t)(r0 + i) * CF + c4];
    }
    // coefficients: one (row, edge) per thread
    if (tid < 16 * KNN) {
        int i = tid / KNN, j = tid % KNN;
        int q = r0 + i;
        int id = edges[q * KNN + j];
        float cf = 0.0f; int s = q;
        if (id >= 0 && id != q) { cf = -disf(deg[id]) * disf(deg[q]); s = id; }
        coef_s[i][j] = cf; nb_s[i][j] = s;
    }
    __syncthreads();
    // gather Tx1 rows: 16*192 = 3072 elements
    for (int e = tid; e < 16 * CF; e += 256) {
        int i = e / CF, c = e % CF;
        float a = 0.0f;
#pragma unroll
        for (int t = 0; t < KNN; ++t)
            a = fmaf(coef_s[i][t], xf[(size_t)nb_s[i][t] * CF + c], a);
        Ax[1][i][c] = a;
    }

    int ty = tid >> 5, tx = tid & 31;    // rows {ty*2,ty*2+1}, cols {tx*2+64m}
    float acc[2][6];
#pragma unroll
    for (int i = 0; i < 2; ++i)
#pragma unroll
        for (int j = 0; j < 6; ++j) acc[i][j] = 0.0f;

    for (int kb = 0; kb < 12; ++kb) {
        __syncthreads();                 // kb=0: Ax[1] ready; else Ws consumed
#pragma unroll
        for (int p = 0; p < 6; ++p)
            *(float4*)&Ws[ww[p]][wr[p]][wc[p]] = pw[p];
        __syncthreads();
        if (kb < 11) {
            size_t off = (size_t)(kb + 1) * 16 * CF;
#pragma unroll
            for (int p = 0; p < 6; ++p) pw[p] = *(const float4*)(wsrc[p] + off);
        }
#pragma unroll
        for (int k = 0; k < 16; ++k) {
            float a0 = Ax[0][ty * 2 + 0][kb * 16 + k];
            float a1 = Ax[0][ty * 2 + 1][kb * 16 + k];
            float g0 = Ax[1][ty * 2 + 0][kb * 16 + k];
            float g1 = Ax[1][ty * 2 + 1][kb * 16 + k];
#pragma unroll
            for (int m = 0; m < 3; ++m) {
                float2 w0 = *(const float2*)&Ws[0][k][tx * 2 + 64 * m];
                float2 w1 = *(const float2*)&Ws[1][k][tx * 2 + 64 * m];
                acc[0][2 * m + 0] = fmaf(a0, w0.x, acc[0][2 * m + 0]);
                acc[0][2 * m + 1] = fmaf(a0, w0.y, acc[0][2 * m + 1]);
                acc[0][2 * m + 0] = fmaf(g0, w1.x, acc[0][2 * m + 0]);
                acc[0][2 * m + 1] = fmaf(g0, w1.y, acc[0][2 * m + 1]);
                acc[1][2 * m + 0] = fmaf(a1, w0.x, acc[1][2 * m + 0]);
                acc[1][2 * m + 1] = fmaf(a1, w0.y, acc[1][2 * m + 1]);
                acc[1][2 * m + 0] = fmaf(g1, w1.x, acc[1][2 * m + 0]);
                acc[1][2 * m + 1] = fmaf(g1, w1.y, acc[1][2 * m + 1]);
            }
        }
    }

#pragma unroll
    for (int i = 0; i < 2; ++i) {
        size_t ro = (size_t)(r0 + ty * 2 + i) * CF;
#pragma unroll
        for (int m = 0; m < 3; ++m) {
            float2 bv = *(const float2*)&bias[tx * 2 + 64 * m];
            float2 o;
            o.x = acc[i][2 * m + 0] + bv.x;
            o.y = acc[i][2 * m + 1] + bv.y;
            *(float2*)&out[ro + tx * 2 + 64 * m] = o;
        }
    }
}

// ---------------------------------------------------------------- launch
extern "C" void kernel_launch(void* const* d_in, const int* in_sizes, int n_in,
                              void* d_out, int out_size, void* d_ws, size_t ws_size,
                              hipStream_t stream)
{
    const float* x    = (const float*)d_in[0];
    const float* W0   = (const float*)d_in[1];
    const float* W1   = (const float*)d_in[2];
    const float* bias = (const float*)d_in[3];
    float* out = (float*)d_out;

    // Workspace: 6.65 MB (known-safe). sq and deg adjacent -> one memset.
    char* ws = (char*)d_ws;
    float* xf    = (float*)ws;  ws += (size_t)NN * CF * 4;   // 6,291,456
    float* sq    = (float*)ws;  ws += (size_t)NN * 4;        //    32,768
    int*   deg   = (int*)ws;    ws += (size_t)NN * 4;        //    32,768
    int*   edges = (int*)ws;    ws += (size_t)NN * KNN * 4;  //   294,912

    // Partial top-k lists live in d_out (2.36 MB of its 6.29 MB); d_out is
    // fully overwritten by out_kernel afterwards, every call.
    float* pk_d = out;                                       // NN*NSPL*KNN
    int*   pk_i = (int*)(out + (size_t)NN * NSPL * KNN);     // NN*NSPL*KNN

    hipMemsetAsync(sq, 0, (size_t)NN * 8, stream);           // sq + deg
    hipLaunchKernelGGL(transpose_kernel, dim3(8, 6, 16), dim3(256), 0, stream, x, xf, sq);
    hipLaunchKernelGGL(knn_kernel, dim3(576), dim3(256), 0, stream, xf, sq, pk_d, pk_i);
    hipLaunchKernelGGL(merge_kernel, dim3(32), dim3(256), 0, stream, pk_d, pk_i, edges, deg);
    hipLaunchKernelGGL(out_kernel, dim3(512), dim3(256), 0, stream,
                       xf, edges, deg, W0, W1, bias, out);
}

// Round 8
// 226.643 us; speedup vs baseline: 1.3264x; 1.3264x over previous
//
#include <hip/hip_runtime.h>
#include <math.h>

#define NN 8192
#define CF 192
#define KNN 9
#define NSPL 4

__device__ __forceinline__ int group_start(int g) {
    // smallest i with batch[i]==g :  ceil(8191*g/8), capped at 8192
    int s = (8191 * g + 7) >> 3;
    return s > 8192 ? 8192 : s;
}

__device__ __forceinline__ float disf(int d) {
    return d > 0 ? 1.0f / sqrtf((float)d) : 0.0f;
}

// ---------------------------------------------------------------- transpose + sq
// x [8,192,32,32] -> xf [8192][192]; also accumulates sq[node] = ||x_f||^2
// via per-32-channel partial sums (half-wave shuffle reduce + atomicAdd).
// sq must be zeroed before launch (memsetAsync covers sq+deg).
__global__ __launch_bounds__(256) void transpose_kernel(
    const float* __restrict__ x, float* __restrict__ xf, float* __restrict__ sq)
{
    __shared__ float tile[32][65];
    int b = blockIdx.x, ct = blockIdx.y, ht = blockIdx.z;
    int c0 = ct * 32, hw0 = ht * 64;
    int tid = threadIdx.x;
#pragma unroll
    for (int p = 0; p < 8; ++p) {
        int c  = p * 4 + (tid >> 6);
        int hw = tid & 63;
        tile[c][hw] = x[(size_t)b * 196608 + (size_t)(c0 + c) * 1024 + hw0 + hw];
    }
    __syncthreads();
#pragma unroll
    for (int p = 0; p < 8; ++p) {
        int hw = p * 8 + (tid >> 5);
        int cc = tid & 31;
        float v = tile[cc][hw];
        xf[(size_t)(b * 1024 + hw0 + hw) * CF + c0 + cc] = v;
        float s = v * v;                 // partial ||.||^2 over this 32-ch slice
#pragma unroll
        for (int off = 16; off > 0; off >>= 1) s += __shfl_xor(s, off, 64);
        if (cc == 0) atomicAdd(&sq[b * 1024 + hw0 + hw], s);
    }
}

// ---------------------------------------------------------------- kNN partial
// grid: 9 groups x 16 query-blocks(64 q) x 4 candidate-splits(256 c) = 576
// blocks; 512 heavy blocks = exactly 2/CU (LDS 55 KB). 8x8 micro-tile:
// 64 B LDS per 64 FMAs -> LDS pipe demand = 128 B/cyc = peak.
// CRITICAL (Round 7 lesson): the selection h-loop MUST be unrolled so acc[][]
// is only ever statically indexed — otherwise acc is demoted to scratch
// (405 MB spill traffic, 2x regression).
__global__ __launch_bounds__(256, 2) void knn_kernel(
    const float* __restrict__ xf, const float* __restrict__ sq,
    float* __restrict__ pk_d, int* __restrict__ pk_i)
{
    int bid = blockIdx.x;
    int g = bid >> 6;
    int rem = bid & 63;
    int qb = rem >> 2;
    int split = rem & 3;
    int gs = group_start(g);
    int gsize = group_start(g + 1) - gs;
    int q0 = qb * 64;
    int nq = gsize - q0; if (nq > 64) nq = 64;
    if (nq <= 0) return;                 // block-uniform; q's covered elsewhere
    int c0 = split * 256;
    int ncc = gsize - c0; if (ncc > 256) ncc = 256;

    int tid = threadIdx.x;

    float td[KNN]; int ti[KNN];
#pragma unroll
    for (int j = 0; j < KNN; ++j) { td[j] = __builtin_inff(); ti[j] = -1; }

    if (ncc <= 0) {                      // block-uniform: empty split
        if (tid < nq) {
            int q = gs + q0 + tid;
            size_t base = ((size_t)q * NSPL + split) * KNN;
#pragma unroll
            for (int j = 0; j < KNN; ++j) { pk_d[base + j] = td[j]; pk_i[base + j] = ti[j]; }
        }
        return;
    }

    // staging region (20992 B), overlaid by phase-1 partial lists (9360+9360 B)
    __shared__ __align__(16) char smem[20992];
    float (*As)[68]  = (float(*)[68])smem;                    // 16x68x4  = 4352
    float (*Bs)[260] = (float(*)[260])(smem + 4352);          // 16x260x4 = 16640
    float (*ld)[KNN][65] = (float(*)[KNN][65])smem;           // 4x9x65x4 = 9360
    int   (*li)[KNN][65] = (int(*)[KNN][65])(smem + 9360);    // 9360
    __shared__ float Ds[64][133];        // dot tile, one 128-col half at a time
    __shared__ float sqc_s[256];
    __shared__ float sqq_s[64];

    int ty = tid >> 5;                   // row group: rows ty*8 .. +7
    int tx = tid & 31;                   // cols tx*4 (half0), 128+tx*4 (half1)

    if (tid < 64) {
        int qo = q0 + tid; if (qo > gsize - 1) qo = gsize - 1;
        sqq_s[tid] = sq[gs + qo];
    }
    {
        int co = c0 + tid;
        sqc_s[tid] = (tid < ncc) ? sq[gs + co] : __builtin_inff();
    }

    float acc[8][8];
#pragma unroll
    for (int i = 0; i < 8; ++i)
#pragma unroll
        for (int j = 0; j < 8; ++j) acc[i][j] = 0.0f;

    for (int kb = 0; kb < 12; ++kb) {
        __syncthreads();
        {                                // As: 64 q-rows x 4 float4 = 256 thr
            int r = tid >> 2, c4 = (tid & 3) * 4;
            int qo = q0 + r; if (qo > gsize - 1) qo = gsize - 1;
            float4 v = *(const float4*)(xf + (size_t)(gs + qo) * CF + kb * 16 + c4);
            As[c4 + 0][r] = v.x; As[c4 + 1][r] = v.y;
            As[c4 + 2][r] = v.z; As[c4 + 3][r] = v.w;
        }
#pragma unroll
        for (int p2 = 0; p2 < 4; ++p2) { // Bs: 256 c-rows x 4 float4
            int t = tid + 256 * p2;
            int r = t >> 2, c4 = (t & 3) * 4;
            int co = c0 + r; if (co > gsize - 1) co = gsize - 1;
            float4 v = *(const float4*)(xf + (size_t)(gs + co) * CF + kb * 16 + c4);
            Bs[c4 + 0][r] = v.x; Bs[c4 + 1][r] = v.y;
            Bs[c4 + 2][r] = v.z; Bs[c4 + 3][r] = v.w;
        }
        __syncthreads();
#pragma unroll
        for (int k = 0; k < 16; ++k) {
            float4 a0 = *(const float4*)&As[k][ty * 8];
            float4 a1 = *(const float4*)&As[k][ty * 8 + 4];
            float4 b0 = *(const float4*)&Bs[k][tx * 4];
            float4 b1 = *(const float4*)&Bs[k][128 + tx * 4];
            float aa[8] = {a0.x, a0.y, a0.z, a0.w, a1.x, a1.y, a1.z, a1.w};
            float bb[8] = {b0.x, b0.y, b0.z, b0.w, b1.x, b1.y, b1.z, b1.w};
#pragma unroll
            for (int i = 0; i < 8; ++i)
#pragma unroll
                for (int j = 0; j < 8; ++j)
                    acc[i][j] = fmaf(aa[i], bb[j], acc[i][j]);
        }
    }

    // ---- selection over two 128-column halves (candidates in index order)
    // h-loop UNROLLED: every acc[][] index below must be compile-time constant.
#pragma unroll
    for (int h = 0; h < 2; ++h) {
        int hb = h * 128;
        __syncthreads();                 // FMA reads / prev phase2 done
        // write this half's dot products: all 256 threads, stride-133 rows
#pragma unroll
        for (int i = 0; i < 8; ++i) {
            float4 v = (h == 0)          // constant-folds under unroll
                ? make_float4(acc[i][0], acc[i][1], acc[i][2], acc[i][3])
                : make_float4(acc[i][4], acc[i][5], acc[i][6], acc[i][7]);
            *(float4*)&Ds[ty * 8 + i][tx * 4] = v;
        }
        __syncthreads();
        // phase1: thread -> (query q = tid&63, chunk ch = tid>>6 of 32 cands)
        {
            int q = tid & 63, ch = tid >> 6;
            float sqq = sqq_s[q];
            float pd[KNN]; int pi[KNN];
#pragma unroll
            for (int j = 0; j < KNN; ++j) { pd[j] = __builtin_inff(); pi[j] = -1; }
            for (int j32 = 0; j32 < 32; ++j32) {
                int c = ch * 32 + j32;
                float d = (sqq - 2.0f * Ds[q][c]) + sqc_s[hb + c];  // inf pad
                if (d < pd[KNN - 1]) {
                    pd[KNN - 1] = d; pi[KNN - 1] = gs + c0 + hb + c;
#pragma unroll
                    for (int j = KNN - 1; j > 0; --j) {
                        if (pd[j] < pd[j - 1]) {
                            float tf = pd[j]; pd[j] = pd[j - 1]; pd[j - 1] = tf;
                            int tn = pi[j]; pi[j] = pi[j - 1]; pi[j - 1] = tn;
                        }
                    }
                }
            }
#pragma unroll
            for (int j = 0; j < KNN; ++j) { ld[ch][j][q] = pd[j]; li[ch][j][q] = pi[j]; }
        }
        __syncthreads();
        // phase2: 64 threads merge 4 sorted lists (index order; early break)
        if (tid < 64) {
            for (int ch = 0; ch < 4; ++ch) {
#pragma unroll
                for (int j0 = 0; j0 < KNN; ++j0) {
                    float d = ld[ch][j0][tid];
                    if (!(d < td[KNN - 1])) break;   // sorted: rest can't insert
                    int id = li[ch][j0][tid];
                    td[KNN - 1] = d; ti[KNN - 1] = id;
#pragma unroll
                    for (int j = KNN - 1; j > 0; --j) {
                        if (td[j] < td[j - 1]) {
                            float tf = td[j]; td[j] = td[j - 1]; td[j - 1] = tf;
                            int tn = ti[j]; ti[j] = ti[j - 1]; ti[j - 1] = tn;
                        }
                    }
                }
            }
        }
    }

    if (tid < nq) {
        int q = gs + q0 + tid;
        size_t base = ((size_t)q * NSPL + split) * KNN;
#pragma unroll
        for (int j = 0; j < KNN; ++j) { pk_d[base + j] = td[j]; pk_i[base + j] = ti[j]; }
    }
}

// ---------------------------------------------------------------- merge + deg
__global__ __launch_bounds__(256) void merge_kernel(
    const float* __restrict__ pk_d, const int* __restrict__ pk_i,
    int* __restrict__ edges, int* __restrict__ deg)
{
    int q = blockIdx.x * 256 + threadIdx.x;
    if (q >= NN) return;
    float td[KNN]; int ti[KNN];
#pragma unroll
    for (int j = 0; j < KNN; ++j) { td[j] = __builtin_inff(); ti[j] = -1; }
    for (int s = 0; s < NSPL; ++s) {       // split order = index order (stable)
        size_t base = ((size_t)q * NSPL + s) * KNN;
#pragma unroll
        for (int j0 = 0; j0 < KNN; ++j0) {
            float d = pk_d[base + j0]; int id = pk_i[base + j0];
            if (d < td[KNN - 1]) {
                td[KNN - 1] = d; ti[KNN - 1] = id;
#pragma unroll
                for (int j = KNN - 1; j > 0; --j) {
                    if (td[j] < td[j - 1]) {
                        float tf = td[j]; td[j] = td[j - 1]; td[j - 1] = tf;
                        int tn = ti[j]; ti[j] = ti[j - 1]; ti[j - 1] = tn;
                    }
                }
            }
        }
    }
#pragma unroll
    for (int j = 0; j < KNN; ++j) {
        int id = ti[j];                   // -1 <=> invalid (d == inf)
        edges[q * KNN + j] = id;
        if (id >= 0 && id != q) atomicAdd(&deg[id], 1);
    }
}

// ---------------------------------------------------------------- fused Tx1 + out GEMM
// One block per 16-row stripe (512 blocks). W0/W1 k-tiles staged together so
// both matmuls accumulate in one kb sweep; W prefetched into registers (OK
// here: (256,2) -> 256-VGPR budget, no spill). LDS 50.3 KB.
__global__ __launch_bounds__(256, 2) void out_kernel(
    const float* __restrict__ xf, const int* __restrict__ edges,
    const int* __restrict__ deg, const float* __restrict__ W0,
    const float* __restrict__ W1, const float* __restrict__ bias,
    float* __restrict__ out)
{
    __shared__ float Ax[2][16][CF];      // [0]=xf rows, [1]=Tx1 rows (24.6 KB)
    __shared__ float Ws[2][16][CF];      // W0/W1 k-tiles (24.6 KB)
    __shared__ float coef_s[16][KNN];
    __shared__ int   nb_s[16][KNN];

    int r0 = blockIdx.x * 16;
    int tid = threadIdx.x;

    // W prefetch setup: 1536 float4 per kb tile, 6 per thread
    const float* wsrc[6];
    int ww[6], wr[6], wc[6];
    float4 pw[6];
#pragma unroll
    for (int p = 0; p < 6; ++p) {
        int f = p * 256 + tid;
        ww[p] = f / 768; wr[p] = (f % 768) / 48; wc[p] = (f % 48) * 4;
        wsrc[p] = (ww[p] ? W1 : W0) + (size_t)wr[p] * CF + wc[p];
        pw[p] = *(const float4*)(wsrc[p]);          // kb = 0
    }

    // stage xf rows: 16 rows x 48 float4 = 768
    for (int t = tid; t < 768; t += 256) {
        int i = t / 48, c4 = (t % 48) * 4;
        *(float4*)&Ax[0][i][c4] = *(const float4*)&xf[(size_t)(r0 + i) * CF + c4];
    }
    // coefficients: one (row, edge) per thread
    if (tid < 16 * KNN) {
        int i = tid / KNN, j = tid % KNN;
        int q = r0 + i;
        int id = edges[q * KNN + j];
        float cf = 0.0f; int s = q;
        if (id >= 0 && id != q) { cf = -disf(deg[id]) * disf(deg[q]); s = id; }
        coef_s[i][j] = cf; nb_s[i][j] = s;
    }
    __syncthreads();
    // gather Tx1 rows: 16*192 = 3072 elements
    for (int e = tid; e < 16 * CF; e += 256) {
        int i = e / CF, c = e % CF;
        float a = 0.0f;
#pragma unroll
        for (int t = 0; t < KNN; ++t)
            a = fmaf(coef_s[i][t], xf[(size_t)nb_s[i][t] * CF + c], a);
        Ax[1][i][c] = a;
    }

    int ty = tid >> 5, tx = tid & 31;    // rows {ty*2,ty*2+1}, cols {tx*2+64m}
    float acc[2][6];
#pragma unroll
    for (int i = 0; i < 2; ++i)
#pragma unroll
        for (int j = 0; j < 6; ++j) acc[i][j] = 0.0f;

    for (int kb = 0; kb < 12; ++kb) {
        __syncthreads();                 // kb=0: Ax[1] ready; else Ws consumed
#pragma unroll
        for (int p = 0; p < 6; ++p)
            *(float4*)&Ws[ww[p]][wr[p]][wc[p]] = pw[p];
        __syncthreads();
        if (kb < 11) {
            size_t off = (size_t)(kb + 1) * 16 * CF;
#pragma unroll
            for (int p = 0; p < 6; ++p) pw[p] = *(const float4*)(wsrc[p] + off);
        }
#pragma unroll
        for (int k = 0; k < 16; ++k) {
            float a0 = Ax[0][ty * 2 + 0][kb * 16 + k];
            float a1 = Ax[0][ty * 2 + 1][kb * 16 + k];
            float g0 = Ax[1][ty * 2 + 0][kb * 16 + k];
            float g1 = Ax[1][ty * 2 + 1][kb * 16 + k];
#pragma unroll
            for (int m = 0; m < 3; ++m) {
                float2 w0 = *(const float2*)&Ws[0][k][tx * 2 + 64 * m];
                float2 w1 = *(const float2*)&Ws[1][k][tx * 2 + 64 * m];
                acc[0][2 * m + 0] = fmaf(a0, w0.x, acc[0][2 * m + 0]);
                acc[0][2 * m + 1] = fmaf(a0, w0.y, acc[0][2 * m + 1]);
                acc[0][2 * m + 0] = fmaf(g0, w1.x, acc[0][2 * m + 0]);
                acc[0][2 * m + 1] = fmaf(g0, w1.y, acc[0][2 * m + 1]);
                acc[1][2 * m + 0] = fmaf(a1, w0.x, acc[1][2 * m + 0]);
                acc[1][2 * m + 1] = fmaf(a1, w0.y, acc[1][2 * m + 1]);
                acc[1][2 * m + 0] = fmaf(g1, w1.x, acc[1][2 * m + 0]);
                acc[1][2 * m + 1] = fmaf(g1, w1.y, acc[1][2 * m + 1]);
            }
        }
    }

#pragma unroll
    for (int i = 0; i < 2; ++i) {
        size_t ro = (size_t)(r0 + ty * 2 + i) * CF;
#pragma unroll
        for (int m = 0; m < 3; ++m) {
            float2 bv = *(const float2*)&bias[tx * 2 + 64 * m];
            float2 o;
            o.x = acc[i][2 * m + 0] + bv.x;
            o.y = acc[i][2 * m + 1] + bv.y;
            *(float2*)&out[ro + tx * 2 + 64 * m] = o;
        }
    }
}

// ---------------------------------------------------------------- launch
extern "C" void kernel_launch(void* const* d_in, const int* in_sizes, int n_in,
                              void* d_out, int out_size, void* d_ws, size_t ws_size,
                              hipStream_t stream)
{
    const float* x    = (const float*)d_in[0];
    const float* W0   = (const float*)d_in[1];
    const float* W1   = (const float*)d_in[2];
    const float* bias = (const float*)d_in[3];
    float* out = (float*)d_out;

    // Workspace: 6.65 MB (known-safe). sq and deg adjacent -> one memset.
    char* ws = (char*)d_ws;
    float* xf    = (float*)ws;  ws += (size_t)NN * CF * 4;   // 6,291,456
    float* sq    = (float*)ws;  ws += (size_t)NN * 4;        //    32,768
    int*   deg   = (int*)ws;    ws += (size_t)NN * 4;        //    32,768
    int*   edges = (int*)ws;    ws += (size_t)NN * KNN * 4;  //   294,912

    // Partial top-k lists live in d_out (2.36 MB of its 6.29 MB); d_out is
    // fully overwritten by out_kernel afterwards, every call.
    float* pk_d = out;                                       // NN*NSPL*KNN
    int*   pk_i = (int*)(out + (size_t)NN * NSPL * KNN);     // NN*NSPL*KNN

    hipMemsetAsync(sq, 0, (size_t)NN * 8, stream);           // sq + deg
    hipLaunchKernelGGL(transpose_kernel, dim3(8, 6, 16), dim3(256), 0, stream, x, xf, sq);
    hipLaunchKernelGGL(knn_kernel, dim3(576), dim3(256), 0, stream, xf, sq, pk_d, pk_i);
    hipLaunchKernelGGL(merge_kernel, dim3(32), dim3(256), 0, stream, pk_d, pk_i, edges, deg);
    hipLaunchKernelGGL(out_kernel, dim3(512), dim3(256), 0, stream,
                       xf, edges, deg, W0, W1, bias, out);
}

// Round 9
// 192.680 us; speedup vs baseline: 1.5602x; 1.1763x over previous
//
#include <hip/hip_runtime.h>
#include <math.h>

#define NN 8192
#define CF 192
#define KNN 9
#define NSPL 4

__device__ __forceinline__ int group_start(int g) {
    // smallest i with batch[i]==g :  ceil(8191*g/8), capped at 8192
    int s = (8191 * g + 7) >> 3;
    return s > 8192 ? 8192 : s;
}

__device__ __forceinline__ float disf(int d) {
    return d > 0 ? 1.0f / sqrtf((float)d) : 0.0f;
}

__device__ __forceinline__ unsigned short f2bf(float f) {
    unsigned u = __float_as_uint(f);
    unsigned r = (u + 0x7FFFu + ((u >> 16) & 1u)) >> 16;   // round-nearest-even
    return (unsigned short)r;
}
__device__ __forceinline__ float bf2f(unsigned short h) {
    return __uint_as_float(((unsigned)h) << 16);
}

// ---------------------------------------------------------------- transpose + sq
// x [8,192,32,32] -> xf [8192][192]; also accumulates sq[node] = ||x_f||^2
// via per-32-channel partial sums (half-wave shuffle reduce + atomicAdd).
// sq must be zeroed before launch (memsetAsync covers sq+deg).
__global__ __launch_bounds__(256) void transpose_kernel(
    const float* __restrict__ x, float* __restrict__ xf, float* __restrict__ sq)
{
    __shared__ float tile[32][65];
    int b = blockIdx.x, ct = blockIdx.y, ht = blockIdx.z;
    int c0 = ct * 32, hw0 = ht * 64;
    int tid = threadIdx.x;
#pragma unroll
    for (int p = 0; p < 8; ++p) {
        int c  = p * 4 + (tid >> 6);
        int hw = tid & 63;
        tile[c][hw] = x[(size_t)b * 196608 + (size_t)(c0 + c) * 1024 + hw0 + hw];
    }
    __syncthreads();
#pragma unroll
    for (int p = 0; p < 8; ++p) {
        int hw = p * 8 + (tid >> 5);
        int cc = tid & 31;
        float v = tile[cc][hw];
        xf[(size_t)(b * 1024 + hw0 + hw) * CF + c0 + cc] = v;
        float s = v * v;                 // partial ||.||^2 over this 32-ch slice
#pragma unroll
        for (int off = 16; off > 0; off >>= 1) s += __shfl_xor(s, off, 64);
        if (cc == 0) atomicAdd(&sq[b * 1024 + hw0 + hw], s);
    }
}

// ---------------------------------------------------------------- kNN partial
// grid: 9 groups x 16 query-blocks(64 q) x 4 candidate-splits(256 c) = 576
// blocks. LDS 39936 B -> 4 blocks/CU (16 waves; VGPR 128 allows exactly 4).
// 8x8 micro-tile (LDS-pipe balanced). Selection in 4 quarters of 64 cols
// (Ds stride 69 -> conflict-free). Round-7 lesson: selection loops fully
// unrolled so acc[][] is only statically indexed (else scratch demotion).
__global__ __launch_bounds__(256, 2) void knn_kernel(
    const float* __restrict__ xf, const float* __restrict__ sq,
    float* __restrict__ pk_d, int* __restrict__ pk_i)
{
    int bid = blockIdx.x;
    int g = bid >> 6;
    int rem = bid & 63;
    int qb = rem >> 2;
    int split = rem & 3;
    int gs = group_start(g);
    int gsize = group_start(g + 1) - gs;
    int q0 = qb * 64;
    int nq = gsize - q0; if (nq > 64) nq = 64;
    if (nq <= 0) return;                 // block-uniform; q's covered elsewhere
    int c0 = split * 256;
    int ncc = gsize - c0; if (ncc > 256) ncc = 256;

    int tid = threadIdx.x;

    float td[KNN]; int ti[KNN];
#pragma unroll
    for (int j = 0; j < KNN; ++j) { td[j] = __builtin_inff(); ti[j] = -1; }

    if (ncc <= 0) {                      // block-uniform: empty split
        if (tid < nq) {
            int q = gs + q0 + tid;
            size_t base = ((size_t)q * NSPL + split) * KNN;
#pragma unroll
            for (int j = 0; j < KNN; ++j) { pk_d[base + j] = td[j]; pk_i[base + j] = ti[j]; }
        }
        return;
    }

    // staging region (20992 B), overlaid by phase-1 partial lists (9360+9360 B)
    __shared__ __align__(16) char smem[20992];
    float (*As)[68]  = (float(*)[68])smem;                    // 16x68x4  = 4352
    float (*Bs)[260] = (float(*)[260])(smem + 4352);          // 16x260x4 = 16640
    float (*ld)[KNN][65] = (float(*)[KNN][65])smem;           // 4x9x65x4 = 9360
    int   (*li)[KNN][65] = (int(*)[KNN][65])(smem + 9360);    // 9360
    __shared__ float Ds[64][69];         // one 64-col quarter at a time (17664)
    __shared__ float sqc_s[256];
    __shared__ float sqq_s[64];

    int ty = tid >> 5;                   // row group: rows ty*8 .. +7
    int tx = tid & 31;                   // cols tx*4 (h0), 128+tx*4 (h1)

    if (tid < 64) {
        int qo = q0 + tid; if (qo > gsize - 1) qo = gsize - 1;
        sqq_s[tid] = sq[gs + qo];
    }
    {
        int co = c0 + tid;
        sqc_s[tid] = (tid < ncc) ? sq[gs + co] : __builtin_inff();
    }

    float acc[8][8];
#pragma unroll
    for (int i = 0; i < 8; ++i)
#pragma unroll
        for (int j = 0; j < 8; ++j) acc[i][j] = 0.0f;

    for (int kb = 0; kb < 12; ++kb) {
        __syncthreads();
        {                                // As: 64 q-rows x 4 float4 = 256 thr
            int r = tid >> 2, c4 = (tid & 3) * 4;
            int qo = q0 + r; if (qo > gsize - 1) qo = gsize - 1;
            float4 v = *(const float4*)(xf + (size_t)(gs + qo) * CF + kb * 16 + c4);
            As[c4 + 0][r] = v.x; As[c4 + 1][r] = v.y;
            As[c4 + 2][r] = v.z; As[c4 + 3][r] = v.w;
        }
#pragma unroll
        for (int p2 = 0; p2 < 4; ++p2) { // Bs: 256 c-rows x 4 float4
            int t = tid + 256 * p2;
            int r = t >> 2, c4 = (t & 3) * 4;
            int co = c0 + r; if (co > gsize - 1) co = gsize - 1;
            float4 v = *(const float4*)(xf + (size_t)(gs + co) * CF + kb * 16 + c4);
            Bs[c4 + 0][r] = v.x; Bs[c4 + 1][r] = v.y;
            Bs[c4 + 2][r] = v.z; Bs[c4 + 3][r] = v.w;
        }
        __syncthreads();
#pragma unroll
        for (int k = 0; k < 16; ++k) {
            float4 a0 = *(const float4*)&As[k][ty * 8];
            float4 a1 = *(const float4*)&As[k][ty * 8 + 4];
            float4 b0 = *(const float4*)&Bs[k][tx * 4];
            float4 b1 = *(const float4*)&Bs[k][128 + tx * 4];
            float aa[8] = {a0.x, a0.y, a0.z, a0.w, a1.x, a1.y, a1.z, a1.w};
            float bb[8] = {b0.x, b0.y, b0.z, b0.w, b1.x, b1.y, b1.z, b1.w};
#pragma unroll
            for (int i = 0; i < 8; ++i)
#pragma unroll
                for (int j = 0; j < 8; ++j)
                    acc[i][j] = fmaf(aa[i], bb[j], acc[i][j]);
        }
    }

    // ---- selection over four 64-column quarters (candidates in index order)
    // qtr loop UNROLLED: every acc[][] index must be compile-time constant.
#pragma unroll
    for (int qtr = 0; qtr < 4; ++qtr) {
        __syncthreads();                 // FMA/phase2 reads done
        // quarter's dot products: cols 64*qtr .. +63. Owner threads:
        // tx>>4 == (qtr&1); acc cols j0..j0+3 with j0 = (qtr>>1)*4.
        if ((tx >> 4) == (qtr & 1)) {
#pragma unroll
            for (int i = 0; i < 8; ++i) {
                float4 v = (qtr < 2)
                    ? make_float4(acc[i][0], acc[i][1], acc[i][2], acc[i][3])
                    : make_float4(acc[i][4], acc[i][5], acc[i][6], acc[i][7]);
                *(float4*)&Ds[ty * 8 + i][(tx & 15) * 4] = v;
            }
        }
        __syncthreads();
        // phase1: thread -> (query q = tid&63, chunk ch = tid>>6 of 16 cands)
        {
            int q = tid & 63, ch = tid >> 6;
            float sqq = sqq_s[q];
            float pd[KNN]; int pi[KNN];
#pragma unroll
            for (int j = 0; j < KNN; ++j) { pd[j] = __builtin_inff(); pi[j] = -1; }
            for (int j16 = 0; j16 < 16; ++j16) {
                int c = ch * 16 + j16;
                float d = (sqq - 2.0f * Ds[q][c]) + sqc_s[qtr * 64 + c];  // inf pad
                if (d < pd[KNN - 1]) {
                    pd[KNN - 1] = d; pi[KNN - 1] = gs + c0 + qtr * 64 + c;
#pragma unroll
                    for (int j = KNN - 1; j > 0; --j) {
                        if (pd[j] < pd[j - 1]) {
                            float tf = pd[j]; pd[j] = pd[j - 1]; pd[j - 1] = tf;
                            int tn = pi[j]; pi[j] = pi[j - 1]; pi[j - 1] = tn;
                        }
                    }
                }
            }
#pragma unroll
            for (int j = 0; j < KNN; ++j) { ld[ch][j][q] = pd[j]; li[ch][j][q] = pi[j]; }
        }
        __syncthreads();
        // phase2: 64 threads merge 4 sorted lists (index order; early break)
        if (tid < 64) {
            for (int ch = 0; ch < 4; ++ch) {
#pragma unroll
                for (int j0 = 0; j0 < KNN; ++j0) {
                    float d = ld[ch][j0][tid];
                    if (!(d < td[KNN - 1])) break;   // sorted: rest can't insert
                    int id = li[ch][j0][tid];
                    td[KNN - 1] = d; ti[KNN - 1] = id;
#pragma unroll
                    for (int j = KNN - 1; j > 0; --j) {
                        if (td[j] < td[j - 1]) {
                            float tf = td[j]; td[j] = td[j - 1]; td[j - 1] = tf;
                            int tn = ti[j]; ti[j] = ti[j - 1]; ti[j - 1] = tn;
                        }
                    }
                }
            }
        }
    }

    if (tid < nq) {
        int q = gs + q0 + tid;
        size_t base = ((size_t)q * NSPL + split) * KNN;
#pragma unroll
        for (int j = 0; j < KNN; ++j) { pk_d[base + j] = td[j]; pk_i[base + j] = ti[j]; }
    }
}

// ---------------------------------------------------------------- merge + deg
__global__ __launch_bounds__(256) void merge_kernel(
    const float* __restrict__ pk_d, const int* __restrict__ pk_i,
    int* __restrict__ edges, int* __restrict__ deg)
{
    int q = blockIdx.x * 256 + threadIdx.x;
    if (q >= NN) return;
    float td[KNN]; int ti[KNN];
#pragma unroll
    for (int j = 0; j < KNN; ++j) { td[j] = __builtin_inff(); ti[j] = -1; }
    for (int s = 0; s < NSPL; ++s) {       // split order = index order (stable)
        size_t base = ((size_t)q * NSPL + s) * KNN;
#pragma unroll
        for (int j0 = 0; j0 < KNN; ++j0) {
            float d = pk_d[base + j0]; int id = pk_i[base + j0];
            if (d < td[KNN - 1]) {
                td[KNN - 1] = d; ti[KNN - 1] = id;
#pragma unroll
                for (int j = KNN - 1; j > 0; --j) {
                    if (td[j] < td[j - 1]) {
                        float tf = td[j]; td[j] = td[j - 1]; td[j - 1] = tf;
                        int tn = ti[j]; ti[j] = ti[j - 1]; ti[j - 1] = tn;
                    }
                }
            }
        }
    }
#pragma unroll
    for (int j = 0; j < KNN; ++j) {
        int id = ti[j];                   // -1 <=> invalid (d == inf)
        edges[q * KNN + j] = id;
        if (id >= 0 && id != q) atomicAdd(&deg[id], 1);
    }
}

// ---------------------------------------------------------------- fused Tx1 + out GEMM
// One block per 16-row stripe (512 blocks). LDS staging in bf16 (halves the
// LDS bytes/FMA that bound this kernel); fp32 accumulate + fp32 epilogue.
// Paired-k reads: Axh pairs over k (b32), Wsh pairs over adjacent cols (b32).
// LDS 25.7 KB.
__global__ __launch_bounds__(256, 2) void out_kernel(
    const float* __restrict__ xf, const int* __restrict__ edges,
    const int* __restrict__ deg, const float* __restrict__ W0,
    const float* __restrict__ W1, const float* __restrict__ bias,
    float* __restrict__ out)
{
    __shared__ unsigned short Axh[2][16][CF];   // [0]=xf, [1]=Tx1 (12288 B)
    __shared__ unsigned short Wsh[2][16][CF];   // W0/W1 k-tiles  (12288 B)
    __shared__ float coef_s[16][KNN];
    __shared__ int   nb_s[16][KNN];

    int r0 = blockIdx.x * 16;
    int tid = threadIdx.x;

    // W prefetch setup: 1536 float4 per kb tile, 6 per thread (fp32 load,
    // bf16 convert on LDS store)
    const float* wsrc[6];
    int ww[6], wr[6], wc[6];
    float4 pw[6];
#pragma unroll
    for (int p = 0; p < 6; ++p) {
        int f = p * 256 + tid;
        ww[p] = f / 768; wr[p] = (f % 768) / 48; wc[p] = (f % 48) * 4;
        wsrc[p] = (ww[p] ? W1 : W0) + (size_t)wr[p] * CF + wc[p];
        pw[p] = *(const float4*)(wsrc[p]);          // kb = 0
    }

    // stage xf rows -> bf16: 16 rows x 48 float4 = 768
    for (int t = tid; t < 768; t += 256) {
        int i = t / 48, c4 = (t % 48) * 4;
        float4 v = *(const float4*)&xf[(size_t)(r0 + i) * CF + c4];
        ushort4 h;
        h.x = f2bf(v.x); h.y = f2bf(v.y); h.z = f2bf(v.z); h.w = f2bf(v.w);
        *(ushort4*)&Axh[0][i][c4] = h;
    }
    // coefficients: one (row, edge) per thread
    if (tid < 16 * KNN) {
        int i = tid / KNN, j = tid % KNN;
        int q = r0 + i;
        int id = edges[q * KNN + j];
        float cf = 0.0f; int s = q;
        if (id >= 0 && id != q) { cf = -disf(deg[id]) * disf(deg[q]); s = id; }
        coef_s[i][j] = cf; nb_s[i][j] = s;
    }
    __syncthreads();
    // gather Tx1 rows -> bf16 pairs: 16*192/2 = 1536 pairs
    for (int e = tid; e < 16 * CF / 2; e += 256) {
        int i = e / 96, c2 = (e % 96) * 2;
        float a0 = 0.0f, a1 = 0.0f;
#pragma unroll
        for (int t = 0; t < KNN; ++t) {
            const float* row = xf + (size_t)nb_s[i][t] * CF + c2;
            float cf = coef_s[i][t];
            a0 = fmaf(cf, row[0], a0);
            a1 = fmaf(cf, row[1], a1);
        }
        ushort2 h; h.x = f2bf(a0); h.y = f2bf(a1);
        *(ushort2*)&Axh[1][i][c2] = h;
    }

    int ty = tid >> 5, tx = tid & 31;    // rows {ty*2,ty*2+1}, cols {tx*2+64m}
    float acc[2][6];
#pragma unroll
    for (int i = 0; i < 2; ++i)
#pragma unroll
        for (int j = 0; j < 6; ++j) acc[i][j] = 0.0f;

    for (int kb = 0; kb < 12; ++kb) {
        __syncthreads();                 // kb=0: Axh[1] ready; else Wsh consumed
#pragma unroll
        for (int p = 0; p < 6; ++p) {
            ushort4 h;
            h.x = f2bf(pw[p].x); h.y = f2bf(pw[p].y);
            h.z = f2bf(pw[p].z); h.w = f2bf(pw[p].w);
            *(ushort4*)&Wsh[ww[p]][wr[p]][wc[p]] = h;
        }
        __syncthreads();
        if (kb < 11) {
            size_t off = (size_t)(kb + 1) * 16 * CF;
#pragma unroll
            for (int p = 0; p < 6; ++p) pw[p] = *(const float4*)(wsrc[p] + off);
        }
#pragma unroll
        for (int k2 = 0; k2 < 8; ++k2) { // k = kb*16 + 2*k2 + {0,1}
            int kk = 2 * k2;
            ushort2 a0p = *(const ushort2*)&Axh[0][ty * 2 + 0][kb * 16 + kk];
            ushort2 a1p = *(const ushort2*)&Axh[0][ty * 2 + 1][kb * 16 + kk];
            ushort2 g0p = *(const ushort2*)&Axh[1][ty * 2 + 0][kb * 16 + kk];
            ushort2 g1p = *(const ushort2*)&Axh[1][ty * 2 + 1][kb * 16 + kk];
            float a0k0 = bf2f(a0p.x), a0k1 = bf2f(a0p.y);
            float a1k0 = bf2f(a1p.x), a1k1 = bf2f(a1p.y);
            float g0k0 = bf2f(g0p.x), g0k1 = bf2f(g0p.y);
            float g1k0 = bf2f(g1p.x), g1k1 = bf2f(g1p.y);
#pragma unroll
            for (int m = 0; m < 3; ++m) {
                ushort2 u00 = *(const ushort2*)&Wsh[0][kk + 0][tx * 2 + 64 * m];
                ushort2 u01 = *(const ushort2*)&Wsh[0][kk + 1][tx * 2 + 64 * m];
                ushort2 u10 = *(const ushort2*)&Wsh[1][kk + 0][tx * 2 + 64 * m];
                ushort2 u11 = *(const ushort2*)&Wsh[1][kk + 1][tx * 2 + 64 * m];
                float w00x = bf2f(u00.x), w00y = bf2f(u00.y);
                float w01x = bf2f(u01.x), w01y = bf2f(u01.y);
                float w10x = bf2f(u10.x), w10y = bf2f(u10.y);
                float w11x = bf2f(u11.x), w11y = bf2f(u11.y);
                acc[0][2*m+0] = fmaf(a0k0, w00x, acc[0][2*m+0]);
                acc[0][2*m+0] = fmaf(a0k1, w01x, acc[0][2*m+0]);
                acc[0][2*m+0] = fmaf(g0k0, w10x, acc[0][2*m+0]);
                acc[0][2*m+0] = fmaf(g0k1, w11x, acc[0][2*m+0]);
                acc[0][2*m+1] = fmaf(a0k0, w00y, acc[0][2*m+1]);
                acc[0][2*m+1] = fmaf(a0k1, w01y, acc[0][2*m+1]);
                acc[0][2*m+1] = fmaf(g0k0, w10y, acc[0][2*m+1]);
                acc[0][2*m+1] = fmaf(g0k1, w11y, acc[0][2*m+1]);
                acc[1][2*m+0] = fmaf(a1k0, w00x, acc[1][2*m+0]);
                acc[1][2*m+0] = fmaf(a1k1, w01x, acc[1][2*m+0]);
                acc[1][2*m+0] = fmaf(g1k0, w10x, acc[1][2*m+0]);
                acc[1][2*m+0] = fmaf(g1k1, w11x, acc[1][2*m+0]);
                acc[1][2*m+1] = fmaf(a1k0, w00y, acc[1][2*m+1]);
                acc[1][2*m+1] = fmaf(a1k1, w01y, acc[1][2*m+1]);
                acc[1][2*m+1] = fmaf(g1k0, w10y, acc[1][2*m+1]);
                acc[1][2*m+1] = fmaf(g1k1, w11y, acc[1][2*m+1]);
            }
        }
    }

#pragma unroll
    for (int i = 0; i < 2; ++i) {
        size_t ro = (size_t)(r0 + ty * 2 + i) * CF;
#pragma unroll
        for (int m = 0; m < 3; ++m) {
            float2 bv = *(const float2*)&bias[tx * 2 + 64 * m];
            float2 o;
            o.x = acc[i][2 * m + 0] + bv.x;
            o.y = acc[i][2 * m + 1] + bv.y;
            *(float2*)&out[ro + tx * 2 + 64 * m] = o;
        }
    }
}

// ---------------------------------------------------------------- launch
extern "C" void kernel_launch(void* const* d_in, const int* in_sizes, int n_in,
                              void* d_out, int out_size, void* d_ws, size_t ws_size,
                              hipStream_t stream)
{
    const float* x    = (const float*)d_in[0];
    const float* W0   = (const float*)d_in[1];
    const float* W1   = (const float*)d_in[2];
    const float* bias = (const float*)d_in[3];
    float* out = (float*)d_out;

    // Workspace: 6.65 MB (known-safe). sq and deg adjacent -> one memset.
    char* ws = (char*)d_ws;
    float* xf    = (float*)ws;  ws += (size_t)NN * CF * 4;   // 6,291,456
    float* sq    = (float*)ws;  ws += (size_t)NN * 4;        //    32,768
    int*   deg   = (int*)ws;    ws += (size_t)NN * 4;        //    32,768
    int*   edges = (int*)ws;    ws += (size_t)NN * KNN * 4;  //   294,912

    // Partial top-k lists live in d_out (2.36 MB of its 6.29 MB); d_out is
    // fully overwritten by out_kernel afterwards, every call.
    float* pk_d = out;                                       // NN*NSPL*KNN
    int*   pk_i = (int*)(out + (size_t)NN * NSPL * KNN);     // NN*NSPL*KNN

    hipMemsetAsync(sq, 0, (size_t)NN * 8, stream);           // sq + deg
    hipLaunchKernelGGL(transpose_kernel, dim3(8, 6, 16), dim3(256), 0, stream, x, xf, sq);
    hipLaunchKernelGGL(knn_kernel, dim3(576), dim3(256), 0, stream, xf, sq, pk_d, pk_i);
    hipLaunchKernelGGL(merge_kernel, dim3(32), dim3(256), 0, stream, pk_d, pk_i, edges, deg);
    hipLaunchKernelGGL(out_kernel, dim3(512), dim3(256), 0, stream,
                       xf, edges, deg, W0, W1, bias, out);
}